// Round 7
// baseline (372.750 us; speedup 1.0000x reference)
//
#include <hip/hip_runtime.h>
#include <stdint.h>

#define TOKENS 65536
#define CDIM 384
#define NEXP 5
#define NPAIR 10
#define CAP 8192               // per-bucket capacity; E[cnt]=6554, sigma~77 -> 21-sigma margin
#define NBLK 1024              // router blocks (64 tokens each)
#define WE_STRIDE (CDIM * CDIM)

typedef __attribute__((ext_vector_type(8))) short short8;
typedef __attribute__((ext_vector_type(4))) float floatx4;

// unordered expert pair id p -> (a,b), a<b; p = a*4 - a*(a-1)/2 + (b-a-1)
__constant__ int PAIR_A[NPAIR] = {0, 0, 0, 0, 1, 1, 1, 2, 2, 3};
__constant__ int PAIR_B[NPAIR] = {1, 2, 3, 4, 2, 3, 4, 3, 4, 4};

__device__ inline unsigned short f2bf(float f) {
    union { float f; uint32_t u; } v; v.f = f;
    uint32_t r = v.u + 0x7fffu + ((v.u >> 16) & 1u);   // RNE for normal values
    return (unsigned short)(r >> 16);
}

__device__ inline void load_lds16(const void* g, void* l) {
    // async global->LDS, 16B/lane; dest = wave-uniform base + lane*16
    __builtin_amdgcn_global_load_lds((const __attribute__((address_space(1))) void*)g,
                                     (__attribute__((address_space(3))) void*)l, 16, 0, 0);
}

// ---------------- Kernel 1: router v8 — no x staging, 4 lanes/token, 100% occupancy -
// v7's 56.8KB LDS capped it at 2 blocks/CU with 6 barriers/block. v8: lane group
// g=lane&3 of each token reads INTERLEAVED 16B granules (elements k*16+g*4): 4 lanes
// = one full 64B line per instruction, perfectly coalesced, NO LDS staging. fp64
// 5-chain partials reduced across the 4 lanes by __shfl_xor tree (fixed order,
// deterministic, reassoc err ~1e-16 -> selection unchanged). LDS = wgs 12KB only ->
// 8 blocks/CU = 32 waves = 100% occupancy.
__global__ __launch_bounds__(256) void router_kernel(const float* __restrict__ x,
                                                     const float* __restrict__ Wg,
                                                     int* __restrict__ blkcnt,
                                                     int* __restrict__ tmeta,
                                                     float2* __restrict__ tgate) {
    __shared__ __align__(16) float wgs[CDIM * 8];        // padded stride 8, 12 KB
    __shared__ int wcnt[4][NPAIR];
    int t = threadIdx.x, lane = t & 63, w = t >> 6;
    int tok0 = blockIdx.x * 64;

    for (int i = t; i < CDIM * NEXP; i += 256) wgs[(i / NEXP) * 8 + (i % NEXP)] = Wg[i];
    __syncthreads();

    int lt = lane >> 2, g = lane & 3;
    int token = tok0 + w * 16 + lt;
    const float4* xb = (const float4*)(x + (size_t)token * CDIM) + g;   // elems k*16+g*4
    double p0 = 0, p1 = 0, p2 = 0, p3 = 0, p4 = 0;
    #pragma unroll
    for (int k = 0; k < 24; ++k) {
        float4 xv = xb[k * 4];
        #pragma unroll
        for (int u = 0; u < 4; ++u) {
            int c = k * 16 + g * 4 + u;
            float xe = (u == 0) ? xv.x : (u == 1) ? xv.y : (u == 2) ? xv.z : xv.w;
            float4 w03 = *(const float4*)&wgs[c * 8];    // 16B-aligned (stride 8)
            float  w4  = wgs[c * 8 + 4];
            double xd = (double)xe;
            p0 += xd * w03.x; p1 += xd * w03.y; p2 += xd * w03.z;
            p3 += xd * w03.w; p4 += xd * w4;
        }
    }
    // 4-lane tree reduce, fixed order ((g0+g1)+(g2+g3)) -- fp64, deterministic
    p0 += __shfl_xor(p0, 1); p1 += __shfl_xor(p1, 1); p2 += __shfl_xor(p2, 1);
    p3 += __shfl_xor(p3, 1); p4 += __shfl_xor(p4, 1);
    p0 += __shfl_xor(p0, 2); p1 += __shfl_xor(p1, 2); p2 += __shfl_xor(p2, 2);
    p3 += __shfl_xor(p3, 2); p4 += __shfl_xor(p4, 2);

    int myp = -1; float ga = 0.0f, gb = 0.0f;
    if (g == 0) {                                        // lane owns its token's logits
        double pa[NEXP] = {p0, p1, p2, p3, p4};
        int i0 = 0; double m0v = pa[0];
        #pragma unroll
        for (int e = 1; e < NEXP; ++e) if (pa[e] > m0v) { m0v = pa[e]; i0 = e; }  // strict >: lax.top_k ties
        int i1 = -1; double m1v = -1e300;
        #pragma unroll
        for (int e = 0; e < NEXP; ++e) if (e != i0 && pa[e] > m1v) { m1v = pa[e]; i1 = e; }
        float d  = (float)(m1v - m0v);
        float e1 = expf(d);
        float inv = 1.0f / (1.0f + e1);                  // gate of i0; gate of i1 = e1*inv
        int a  = i0 < i1 ? i0 : i1;
        int b2 = i0 < i1 ? i1 : i0;
        myp = a * 4 - ((a * (a - 1)) >> 1) + (b2 - a - 1);
        ga = (a == i0) ? inv : e1 * inv;                 // gate of lower-indexed expert
        gb = (a == i0) ? e1 * inv : inv;
    }
    // per-wave ballot histogram over own-lanes (own-lane order == token order)
    unsigned long long below = (1ull << lane) - 1ull;
    int myrank = 0, myh = 0;
    #pragma unroll
    for (int e = 0; e < NPAIR; ++e) {
        unsigned long long mask = __ballot(myp == e);
        if (myp == e)  myrank = (int)__popcll(mask & below);
        if (lane == e) myh    = (int)__popcll(mask);
    }
    if (lane < NPAIR) wcnt[w][lane] = myh;
    __syncthreads();
    if (g == 0) {
        int woff = 0;
        #pragma unroll
        for (int k = 0; k < 4; ++k) if (k < w) woff += wcnt[k][myp];
        tmeta[token] = myp | ((woff + myrank) << 8);     // p<10, rank<64
        tgate[token] = make_float2(ga, gb);
    }
    if (t < NPAIR)
        blkcnt[t * NBLK + blockIdx.x] = wcnt[0][t] + wcnt[1][t] + wcnt[2][t] + wcnt[3][t];
}

// ---------------- Kernel 2: FUSED scan+scatter+convert (unchanged control) ----------
__global__ __launch_bounds__(256) void mid_kernel(const int* __restrict__ blkcnt,
                                                  const int* __restrict__ tmeta,
                                                  int* __restrict__ bidx,
                                                  int* __restrict__ cnt,
                                                  const float* __restrict__ We,
                                                  unsigned short* __restrict__ WeT) {
    __shared__ float tile[64][65];                       // convert branch (16.6 KB)
    __shared__ int   sbase[NPAIR][4];                    // scatter branch
    __shared__ int   rred[4];
    int bid = blockIdx.x;
    int t = threadIdx.x;

    if (bid >= 256) {
        // ---- convert part: We[e][c][d] fp32 -> WeT[e][d][c] bf16 (tiled transpose)
        int idx = bid - 256;                             // 0..179
        int e   = idx / 36, rem = idx % 36;
        int c0  = (rem / 6) * 64, d0 = (rem % 6) * 64;
        const float* src = We + (size_t)e * WE_STRIDE;
        int dr = t & 15, cr = t >> 4;
        for (int s = 0; s < 64; s += 16) {
            float4 v = *(const float4*)&src[(size_t)(c0 + cr + s) * CDIM + d0 + dr * 4];
            tile[cr + s][dr * 4 + 0] = v.x;
            tile[cr + s][dr * 4 + 1] = v.y;
            tile[cr + s][dr * 4 + 2] = v.z;
            tile[cr + s][dr * 4 + 3] = v.w;
        }
        __syncthreads();
        unsigned short* dst = WeT + (size_t)e * WE_STRIDE;
        int c4 = t & 15, drow = t >> 4;
        for (int s = 0; s < 64; s += 16) {
            int d = drow + s;
            ushort4 o;
            o.x = f2bf(tile[c4 * 4 + 0][d]);
            o.y = f2bf(tile[c4 * 4 + 1][d]);
            o.z = f2bf(tile[c4 * 4 + 2][d]);
            o.w = f2bf(tile[c4 * 4 + 3][d]);
            *(ushort4*)&dst[(size_t)(d0 + d) * CDIM + c0 + c4 * 4] = o;
        }
        return;
    }

    // ---- scatter part: tokens [bid*256, bid*256+256) = token-blocks 4b..4b+3 ------
    int lane = t & 63, w = t >> 6;
    int nb4 = bid * 4;
    for (int p = 0; p < NPAIR; ++p) {
        int s = 0;
        for (int j = t; j < nb4; j += 256) s += blkcnt[p * NBLK + j];
        #pragma unroll
        for (int d = 1; d < 64; d <<= 1) s += __shfl_xor(s, d);      // full-wave sum
        if (lane == 0) rred[w] = s;
        __syncthreads();
        if (t == 0) {
            int S  = rred[0] + rred[1] + rred[2] + rred[3];          // excl prefix before tb=4b
            int c0_ = blkcnt[p * NBLK + nb4 + 0];
            int c1_ = blkcnt[p * NBLK + nb4 + 1];
            int c2_ = blkcnt[p * NBLK + nb4 + 2];
            sbase[p][0] = S;
            sbase[p][1] = S + c0_;
            sbase[p][2] = S + c0_ + c1_;
            sbase[p][3] = S + c0_ + c1_ + c2_;
            if (bid == 255) cnt[p] = S + c0_ + c1_ + c2_ + blkcnt[p * NBLK + nb4 + 3];
        }
        __syncthreads();                                 // sbase ready; rred reusable
    }
    int tok  = bid * 256 + t;
    int meta = tmeta[tok];
    int p    = meta & 255, rank = meta >> 8;
    int pos  = sbase[p][t >> 6] + rank;
    if (pos < CAP) bidx[p * CAP + pos] = tok;
}

// ---------------- Kernel 3: grouped GEMM v4 — 128x64 tile, reg-A, 3 blocks/CU -------
// Register accounting: 128x128 tile = acc 64 + ~64 working = 128 regs -> hard 2
// blocks/CU cap (the 80% stall can't be hidden). v4: 128x64 tile (acc 32), A-frags
// loaded DIRECTLY to registers from x (no A-LDS / staging barrier), B tribuf 24 KB
// -> 3 blocks/CU (24 waves). Counted vmcnt: 1 B-DMA/thread/kc; xf loads issue before
// the DMA each iteration so the implicit xf-wait drains exactly through B[kc],
// leaving B[kc+1] in flight -> vmcnt(1) at barriers (vmcnt(0) only kc=0).
__global__ __launch_bounds__(512, 6) void moe_kernel(const float* __restrict__ x,
                                                     const unsigned short* __restrict__ WeT,
                                                     const int* __restrict__ cnt,
                                                     const int* __restrict__ bidx,
                                                     const float2* __restrict__ tgate,
                                                     const float* __restrict__ be,
                                                     float* __restrict__ out) {
    // grid 3840 = 8*480: bijective XCD-chunk swizzle; the 6 n-tiles of one (p,mt)
    // A-panel are consecutive bids -> same XCD L2.
    int bh  = blockIdx.x;
    int bid = (bh & 7) * 480 + (bh >> 3);
    int pq  = bid / 6;                    // p*64 + mt
    int nt  = bid - pq * 6;
    int p   = pq >> 6;
    int mt  = pq & 63;

    int nct = cnt[p];
    int m0  = mt * 128;
    if (m0 >= nct) return;                // block-uniform early exit (before any barrier)
    int valid = nct - m0; if (valid > 128) valid = 128;

    int ea = PAIR_A[p], eb = PAIR_B[p];
    int n0 = nt * 64;
    int t = threadIdx.x, lane = t & 63, wid = t >> 6;
    int wm = wid >> 1, wn = wid & 1;      // 4(m) x 2(n) waves -> wave tile 32x32
    int q = lane >> 4, cc = lane & 15;

    // granules (16B): B tribuf only, 3 x 512 = 1536 granules = 24 KB
    __shared__ __align__(16) unsigned short S[1536 * 8];

    floatx4 acc[2][2][2];                 // [expert a/b][m-sub][n-sub] = 32 regs
    #pragma unroll
    for (int e = 0; e < 2; ++e)
        #pragma unroll
        for (int i = 0; i < 2; ++i)
            #pragma unroll
            for (int j = 0; j < 2; ++j)
                acc[e][i][j] = (floatx4){0.0f, 0.0f, 0.0f, 0.0f};

    // B staging via DMA: 512 granules/kc, exactly 1/thread
    int et = t >> 8, pe = t & 255, r = pe >> 2, gp = pe & 3;
    int gl = (gp - (r >> 1)) & 3;         // conflict-free k-granule perm (verified)
    int esel = et ? eb : ea;
    const unsigned short* bsrc = WeT + (size_t)esel * WE_STRIDE + (size_t)(n0 + r) * CDIM + gl * 8;
    int bdst = wid * 64;                  // granule within B buf (+lane via DMA)

    // A direct-fragment addressing: lane owns rows wm*32+cc, +16; k-slice q*8..q*8+7
    int r0 = wm * 32 + cc, r1 = r0 + 16;
    int gid0 = bidx[p * CAP + m0 + (r0 < valid ? r0 : valid - 1)];
    int gid1 = bidx[p * CAP + m0 + (r1 < valid ? r1 : valid - 1)];
    const float* xa0 = x + (size_t)gid0 * CDIM + q * 8;
    const float* xa1 = x + (size_t)gid1 * CDIM + q * 8;

    // fragment read base (loop-invariant perm: (row>>1)&3 == (cc>>1)&3)
    int perm = (q + (cc >> 1)) & 3;
    int b_gr = 4 * (wn * 32 + cc) + perm;                // + 256*e + 64*j + bb*512

    // prologue: DMA B[0]->buf0, B[1]->buf1 FIRST, then xf[0] (FIFO: xf-wait drains B)
    load_lds16(bsrc,      S + (size_t)(0 * 512 + bdst) * 8);
    load_lds16(bsrc + 32, S + (size_t)(1 * 512 + bdst) * 8);
    float4 xf0, xf1, xf2, xf3;
    xf0 = *(const float4*)(xa0);
    xf1 = *(const float4*)(xa0 + 4);
    xf2 = *(const float4*)(xa1);
    xf3 = *(const float4*)(xa1 + 4);

    #pragma unroll
    for (int kc = 0; kc < 12; ++kc) {
        int bb = kc - (kc / 3) * 3;       // B buffer (kc%3, constant-folded)
        // convert xf (loaded one iteration ago; implicit wait drains through B[kc])
        short8 af0, af1;
        af0[0] = f2bf(xf0.x); af0[1] = f2bf(xf0.y); af0[2] = f2bf(xf0.z); af0[3] = f2bf(xf0.w);
        af0[4] = f2bf(xf1.x); af0[5] = f2bf(xf1.y); af0[6] = f2bf(xf1.z); af0[7] = f2bf(xf1.w);
        af1[0] = f2bf(xf2.x); af1[1] = f2bf(xf2.y); af1[2] = f2bf(xf2.z); af1[3] = f2bf(xf2.w);
        af1[4] = f2bf(xf3.x); af1[5] = f2bf(xf3.y); af1[6] = f2bf(xf3.z); af1[7] = f2bf(xf3.w);

        if (kc == 0) { asm volatile("s_waitcnt vmcnt(0)" ::: "memory"); }
        else         { asm volatile("s_waitcnt vmcnt(1)" ::: "memory"); }
        __builtin_amdgcn_s_barrier();
        __builtin_amdgcn_sched_barrier(0);

        if (kc < 11) {                    // xf[kc+1] loads BEFORE next DMA (FIFO order)
            int k1 = (kc + 1) * 32;
            xf0 = *(const float4*)(xa0 + k1);
            xf1 = *(const float4*)(xa0 + k1 + 4);
            xf2 = *(const float4*)(xa1 + k1);
            xf3 = *(const float4*)(xa1 + k1 + 4);
        }
        if (kc < 10) {                    // B[kc+2] -> buf (kc+2)%3 (readers done)
            int k2 = (kc + 2) * 32;
            int nb = (kc + 2) % 3;
            load_lds16(bsrc + k2, S + (size_t)(nb * 512 + bdst) * 8);
        }

        int bo = bb * 512;
        __builtin_amdgcn_s_setprio(1);
        #pragma unroll
        for (int e = 0; e < 2; ++e) {
            #pragma unroll
            for (int j = 0; j < 2; ++j) {
                short8 bf = *(const short8*)&S[(size_t)(bo + b_gr + e * 256 + j * 64) * 8];
                acc[e][0][j] = __builtin_amdgcn_mfma_f32_16x16x32_bf16(af0, bf, acc[e][0][j], 0, 0, 0);
                acc[e][1][j] = __builtin_amdgcn_mfma_f32_16x16x32_bf16(af1, bf, acc[e][1][j], 0, 0, 0);
            }
        }
        __builtin_amdgcn_s_setprio(0);
    }

    // ---- epilogue: gates+indices to LDS, combine + bias + leaky, scatter store -----
    __syncthreads();                      // full drain before reusing S
    float2* Gp = (float2*)S;                             // 128 * 8B = 1 KB
    int*    Ip = (int*)((char*)S + 1024);                // 128 * 4B
    if (t < 128) {
        int rr = m0 + (t < valid ? t : valid - 1);
        int gid = bidx[p * CAP + rr];
        Ip[t] = gid;
        Gp[t] = tgate[gid];
    }
    float ba_[2], bb_[2];
    #pragma unroll
    for (int j = 0; j < 2; ++j) {
        int oc = n0 + wn * 32 + j * 16 + cc;
        ba_[j] = be[ea * CDIM + oc];
        bb_[j] = be[eb * CDIM + oc];
    }
    __syncthreads();

    #pragma unroll
    for (int i = 0; i < 2; ++i) {
        #pragma unroll
        for (int rr4 = 0; rr4 < 4; ++rr4) {
            int trow = wm * 32 + i * 16 + q * 4 + rr4;   // C/D: col=cc, row=q*4+rr4
            if (trow < valid) {
                float2 g = Gp[trow];
                int gid  = Ip[trow];
                #pragma unroll
                for (int j = 0; j < 2; ++j) {
                    int oc = n0 + wn * 32 + j * 16 + cc;
                    float v = g.x * (acc[0][i][j][rr4] + ba_[j])
                            + g.y * (acc[1][i][j][rr4] + bb_[j]);
                    v = v > 0.0f ? v : 0.01f * v;
                    out[(size_t)gid * CDIM + oc] = v;
                }
            }
        }
    }
}

extern "C" void kernel_launch(void* const* d_in, const int* in_sizes, int n_in,
                              void* d_out, int out_size, void* d_ws, size_t ws_size,
                              hipStream_t stream) {
    const float* x  = (const float*)d_in[0];
    const float* Wg = (const float*)d_in[1];
    const float* We = (const float*)d_in[2];
    const float* be = (const float*)d_in[3];
    float* out = (float*)d_out;

    // ws layout (16B-aligned sections), total ~2.67 MB:
    //   cnt[10]            @ 0       (pad 256)
    //   bidx  10*8192*4    @ 256         = 327680
    //   blkcnt 10*1024*4   @ 327936      = 40960
    //   (gap)              @ 368896      = 40960
    //   tmeta  65536*4     @ 409856      = 262144
    //   tgate  65536*8     @ 672000      = 524288
    //   WeT    5*384*384*2 @ 1196288     = 1474560
    char* ws = (char*)d_ws;
    int*            cnt    = (int*)ws;
    int*            bidx   = (int*)(ws + 256);
    int*            blkcnt = (int*)(ws + 327936);
    int*            tmeta  = (int*)(ws + 409856);
    float2*         tgate  = (float2*)(ws + 672000);
    unsigned short* WeT    = (unsigned short*)(ws + 1196288);

    router_kernel<<<NBLK, 256, 0, stream>>>(x, Wg, blkcnt, tmeta, tgate);
    mid_kernel<<<436, 256, 0, stream>>>(blkcnt, tmeta, bidx, cnt, We, WeT);
    moe_kernel<<<NPAIR * 64 * 6, 512, 0, stream>>>(x, WeT, cnt, bidx, tgate, be, out);
}

// Round 9
// 280.417 us; speedup vs baseline: 1.3293x; 1.3293x over previous
//
#include <hip/hip_runtime.h>
#include <stdint.h>

#define TOKENS 65536
#define CDIM 384
#define NEXP 5
#define NPAIR 10
#define CAP 8192               // per-bucket capacity; E[cnt]=6554, sigma~77 -> 21-sigma margin
#define NBLK 1024              // router blocks (64 tokens each)
#define WE_STRIDE (CDIM * CDIM)

typedef __attribute__((ext_vector_type(8))) short short8;
typedef __attribute__((ext_vector_type(4))) float floatx4;

// unordered expert pair id p -> (a,b), a<b; p = a*4 - a*(a-1)/2 + (b-a-1)
__constant__ int PAIR_A[NPAIR] = {0, 0, 0, 0, 1, 1, 1, 2, 2, 3};
__constant__ int PAIR_B[NPAIR] = {1, 2, 3, 4, 2, 3, 4, 3, 4, 4};

__device__ inline unsigned short f2bf(float f) {
    union { float f; uint32_t u; } v; v.f = f;
    uint32_t r = v.u + 0x7fffu + ((v.u >> 16) & 1u);   // RNE for normal values
    return (unsigned short)(r >> 16);
}

__device__ inline void load_lds16(const void* g, void* l) {
    // async global->LDS, 16B/lane; dest = wave-uniform base + lane*16
    __builtin_amdgcn_global_load_lds((const __attribute__((address_space(1))) void*)g,
                                     (__attribute__((address_space(3))) void*)l, 16, 0, 0);
}

// ---------------- Kernel 1: router v8 — no x staging, 4 lanes/token (unchanged) -----
__global__ __launch_bounds__(256) void router_kernel(const float* __restrict__ x,
                                                     const float* __restrict__ Wg,
                                                     int* __restrict__ blkcnt,
                                                     int* __restrict__ tmeta,
                                                     float2* __restrict__ tgate) {
    __shared__ __align__(16) float wgs[CDIM * 8];        // padded stride 8, 12 KB
    __shared__ int wcnt[4][NPAIR];
    int t = threadIdx.x, lane = t & 63, w = t >> 6;
    int tok0 = blockIdx.x * 64;

    for (int i = t; i < CDIM * NEXP; i += 256) wgs[(i / NEXP) * 8 + (i % NEXP)] = Wg[i];
    __syncthreads();

    int lt = lane >> 2, g = lane & 3;
    int token = tok0 + w * 16 + lt;
    const float4* xb = (const float4*)(x + (size_t)token * CDIM) + g;   // elems k*16+g*4
    double p0 = 0, p1 = 0, p2 = 0, p3 = 0, p4 = 0;
    #pragma unroll
    for (int k = 0; k < 24; ++k) {
        float4 xv = xb[k * 4];
        #pragma unroll
        for (int u = 0; u < 4; ++u) {
            int c = k * 16 + g * 4 + u;
            float xe = (u == 0) ? xv.x : (u == 1) ? xv.y : (u == 2) ? xv.z : xv.w;
            float4 w03 = *(const float4*)&wgs[c * 8];    // 16B-aligned (stride 8)
            float  w4  = wgs[c * 8 + 4];
            double xd = (double)xe;
            p0 += xd * w03.x; p1 += xd * w03.y; p2 += xd * w03.z;
            p3 += xd * w03.w; p4 += xd * w4;
        }
    }
    // 4-lane tree reduce, fixed order ((g0+g1)+(g2+g3)) -- fp64, deterministic
    p0 += __shfl_xor(p0, 1); p1 += __shfl_xor(p1, 1); p2 += __shfl_xor(p2, 1);
    p3 += __shfl_xor(p3, 1); p4 += __shfl_xor(p4, 1);
    p0 += __shfl_xor(p0, 2); p1 += __shfl_xor(p1, 2); p2 += __shfl_xor(p2, 2);
    p3 += __shfl_xor(p3, 2); p4 += __shfl_xor(p4, 2);

    int myp = -1; float ga = 0.0f, gb = 0.0f;
    if (g == 0) {                                        // lane owns its token's logits
        double pa[NEXP] = {p0, p1, p2, p3, p4};
        int i0 = 0; double m0v = pa[0];
        #pragma unroll
        for (int e = 1; e < NEXP; ++e) if (pa[e] > m0v) { m0v = pa[e]; i0 = e; }  // strict >: lax.top_k ties
        int i1 = -1; double m1v = -1e300;
        #pragma unroll
        for (int e = 0; e < NEXP; ++e) if (e != i0 && pa[e] > m1v) { m1v = pa[e]; i1 = e; }
        float d  = (float)(m1v - m0v);
        float e1 = expf(d);
        float inv = 1.0f / (1.0f + e1);                  // gate of i0; gate of i1 = e1*inv
        int a  = i0 < i1 ? i0 : i1;
        int b2 = i0 < i1 ? i1 : i0;
        myp = a * 4 - ((a * (a - 1)) >> 1) + (b2 - a - 1);
        ga = (a == i0) ? inv : e1 * inv;                 // gate of lower-indexed expert
        gb = (a == i0) ? e1 * inv : inv;
    }
    // per-wave ballot histogram over own-lanes (own-lane order == token order)
    unsigned long long below = (1ull << lane) - 1ull;
    int myrank = 0, myh = 0;
    #pragma unroll
    for (int e = 0; e < NPAIR; ++e) {
        unsigned long long mask = __ballot(myp == e);
        if (myp == e)  myrank = (int)__popcll(mask & below);
        if (lane == e) myh    = (int)__popcll(mask);
    }
    if (lane < NPAIR) wcnt[w][lane] = myh;
    __syncthreads();
    if (g == 0) {
        int woff = 0;
        #pragma unroll
        for (int k = 0; k < 4; ++k) if (k < w) woff += wcnt[k][myp];
        tmeta[token] = myp | ((woff + myrank) << 8);     // p<10, rank<64
        tgate[token] = make_float2(ga, gb);
    }
    if (t < NPAIR)
        blkcnt[t * NBLK + blockIdx.x] = wcnt[0][t] + wcnt[1][t] + wcnt[2][t] + wcnt[3][t];
}

// ---------------- Kernel 2: FUSED scan+scatter+convert (unchanged) ------------------
__global__ __launch_bounds__(256) void mid_kernel(const int* __restrict__ blkcnt,
                                                  const int* __restrict__ tmeta,
                                                  int* __restrict__ bidx,
                                                  int* __restrict__ cnt,
                                                  const float* __restrict__ We,
                                                  unsigned short* __restrict__ WeT) {
    __shared__ float tile[64][65];                       // convert branch (16.6 KB)
    __shared__ int   sbase[NPAIR][4];                    // scatter branch
    __shared__ int   rred[4];
    int bid = blockIdx.x;
    int t = threadIdx.x;

    if (bid >= 256) {
        // ---- convert part: We[e][c][d] fp32 -> WeT[e][d][c] bf16 (tiled transpose)
        int idx = bid - 256;                             // 0..179
        int e   = idx / 36, rem = idx % 36;
        int c0  = (rem / 6) * 64, d0 = (rem % 6) * 64;
        const float* src = We + (size_t)e * WE_STRIDE;
        int dr = t & 15, cr = t >> 4;
        for (int s = 0; s < 64; s += 16) {
            float4 v = *(const float4*)&src[(size_t)(c0 + cr + s) * CDIM + d0 + dr * 4];
            tile[cr + s][dr * 4 + 0] = v.x;
            tile[cr + s][dr * 4 + 1] = v.y;
            tile[cr + s][dr * 4 + 2] = v.z;
            tile[cr + s][dr * 4 + 3] = v.w;
        }
        __syncthreads();
        unsigned short* dst = WeT + (size_t)e * WE_STRIDE;
        int c4 = t & 15, drow = t >> 4;
        for (int s = 0; s < 64; s += 16) {
            int d = drow + s;
            ushort4 o;
            o.x = f2bf(tile[c4 * 4 + 0][d]);
            o.y = f2bf(tile[c4 * 4 + 1][d]);
            o.z = f2bf(tile[c4 * 4 + 2][d]);
            o.w = f2bf(tile[c4 * 4 + 3][d]);
            *(ushort4*)&dst[(size_t)(d0 + d) * CDIM + c0 + c4 * 4] = o;
        }
        return;
    }

    // ---- scatter part: tokens [bid*256, bid*256+256) = token-blocks 4b..4b+3 ------
    int lane = t & 63, w = t >> 6;
    int nb4 = bid * 4;
    for (int p = 0; p < NPAIR; ++p) {
        int s = 0;
        for (int j = t; j < nb4; j += 256) s += blkcnt[p * NBLK + j];
        #pragma unroll
        for (int d = 1; d < 64; d <<= 1) s += __shfl_xor(s, d);      // full-wave sum
        if (lane == 0) rred[w] = s;
        __syncthreads();
        if (t == 0) {
            int S  = rred[0] + rred[1] + rred[2] + rred[3];          // excl prefix before tb=4b
            int c0_ = blkcnt[p * NBLK + nb4 + 0];
            int c1_ = blkcnt[p * NBLK + nb4 + 1];
            int c2_ = blkcnt[p * NBLK + nb4 + 2];
            sbase[p][0] = S;
            sbase[p][1] = S + c0_;
            sbase[p][2] = S + c0_ + c1_;
            sbase[p][3] = S + c0_ + c1_ + c2_;
            if (bid == 255) cnt[p] = S + c0_ + c1_ + c2_ + blkcnt[p * NBLK + nb4 + 3];
        }
        __syncthreads();                                 // sbase ready; rred reusable
    }
    int tok  = bid * 256 + t;
    int meta = tmeta[tok];
    int p    = meta & 255, rank = meta >> 8;
    int pos  = sbase[p][t >> 6] + rank;
    if (pos < CAP) bidx[p * CAP + pos] = tok;
}

// ---------------- Kernel 3: grouped GEMM v6 — 128x128, BK=64, race-free -------------
// Round-8 post-mortem: v5 FAILED (absmax 0.479) from a real race -- B[kc+1] DMA was
// issued PRE-barrier into a DOUBLE buffer whose previous readers (step kc-1's MFMA
// ds_reads on other waves) only drain at barrier(kc). v6 keeps BK=64 (6 K-steps, the
// step-law lever) but restores the r4-verified race-free shape: prefetch issued
// AFTER the barrier (target buffer's readers drained before that barrier by
// construction), full vmcnt(0)+lgkmcnt(0) at the barrier (only B[kc] outstanding
// there -- counted wait has nothing to keep in flight; r4-vs-r5 measured that delta
// at ~3us/12 steps). LDS 96KB (proven size): A dbuf 32KB + B dbuf 64KB. 1 block/CU.
__global__ __launch_bounds__(512, 2) void moe_kernel(const float* __restrict__ x,
                                                     const unsigned short* __restrict__ WeT,
                                                     const int* __restrict__ cnt,
                                                     const int* __restrict__ bidx,
                                                     const float2* __restrict__ tgate,
                                                     const float* __restrict__ be,
                                                     float* __restrict__ out) {
    // grid 1920 = 8*240: bijective XCD-chunk swizzle
    int bh  = blockIdx.x;
    int bid = (bh & 7) * 240 + (bh >> 3);
    int pq  = bid / 3;                    // p*64 + mt
    int nt  = bid - pq * 3;
    int p   = pq >> 6;
    int mt  = pq & 63;

    int nct = cnt[p];
    int m0  = mt * 128;
    if (m0 >= nct) return;                // block-uniform early exit (before any barrier)
    int valid = nct - m0; if (valid > 128) valid = 128;

    int ea = PAIR_A[p], eb = PAIR_B[p];
    int n0 = nt * 128;
    int t = threadIdx.x, lane = t & 63, wid = t >> 6;
    int wm = wid >> 1, wn = wid & 1;      // 4(m) x 2(n) waves -> wave tile 32x64
    int q = lane >> 4, cc = lane & 15;

    // granules (16B): A dbuf 0..2047 (1024/buf: 2 k-halves x 512), B dbuf 2048..6143
    // (2048/buf: 2 k-halves x {2 experts x 512}) => 96 KB
    __shared__ __align__(16) unsigned short S[6144 * 8];

    floatx4 acc[2][2][4];                 // [expert a/b][m-sub][n-sub]
    #pragma unroll
    for (int e = 0; e < 2; ++e)
        #pragma unroll
        for (int i = 0; i < 2; ++i)
            #pragma unroll
            for (int j = 0; j < 4; ++j)
                acc[e][i][j] = (floatx4){0.0f, 0.0f, 0.0f, 0.0f};

    // B staging via DMA: 2048 granules/step, 4/thread. rep r: gidx = r*512+wid*64+lane
    //   h=(gidx>>10) k-half, e=(gidx>>9)&1 expert (both wave-uniform within a rep),
    //   nrow=(gidx>>2)&127, phys slot gp=gidx&3 holds logical k-granule
    //   gl=(gp-(nrow>>1))&3 (the verified conflict-free perm).
    const unsigned short* bsrc[4];
    int bdstg[4];
    #pragma unroll
    for (int r = 0; r < 4; ++r) {
        int G0 = r * 512 + wid * 64;
        int gidx = G0 + lane;
        int h  = gidx >> 10;
        int e  = (gidx >> 9) & 1;
        int nrow = (gidx >> 2) & 127;
        int gp = gidx & 3;
        int gl = (gp - (nrow >> 1)) & 3;
        int esel = e ? eb : ea;
        bsrc[r]  = WeT + (size_t)esel * WE_STRIDE + (size_t)(n0 + nrow) * CDIM + h * 32 + gl * 8;
        bdstg[r] = 2048 + h * 1024 + e * 512 + (G0 & 511);   // + buf*2048 (+lane via DMA)
    }

    // A staging: thread -> (gathered row, logical k-granule sp within each 32-half)
    int srow = t >> 2, sp = t & 3;
    int arow = m0 + (srow < valid ? srow : valid - 1);   // clamp: ragged last tile
    int gi = bidx[p * CAP + arow];
    const float* xrow = x + (size_t)gi * CDIM + sp * 8;
    int aw0 = 4 * srow + ((sp + (srow >> 1)) & 3);       // + h*512 + buf*1024

    // fragment read bases (loop-invariant perm: (row>>1)&3 == (cc>>1)&3)
    int perm = (q + (cc >> 1)) & 3;
    int a_gr = 4 * (wm * 32 + cc) + perm;                // + kk*512 + 64*i + buf*1024
    int b_gr = 4 * (wn * 64 + cc) + perm;                // + 2048+buf*2048+kk*1024+e*512+64*j

    // prologue: x[0] (4 float4, issued FIRST) then B[0] DMA -> buf0
    float4 xf0 = *(const float4*)(xrow);
    float4 xf1 = *(const float4*)(xrow + 4);
    float4 xf2 = *(const float4*)(xrow + 32);
    float4 xf3 = *(const float4*)(xrow + 36);
    #pragma unroll
    for (int r = 0; r < 4; ++r)
        load_lds16(bsrc[r], S + (size_t)bdstg[r] * 8);

    #pragma unroll
    for (int kc = 0; kc < 6; ++kc) {
        int ab = (kc & 1) * 1024;
        int bb = 2048 + (kc & 1) * 2048;
        // convert x[kc] -> A[buf] (compiler's implicit wait drains only the x loads)
        short8 av0, av1;
        av0[0] = f2bf(xf0.x); av0[1] = f2bf(xf0.y); av0[2] = f2bf(xf0.z); av0[3] = f2bf(xf0.w);
        av0[4] = f2bf(xf1.x); av0[5] = f2bf(xf1.y); av0[6] = f2bf(xf1.z); av0[7] = f2bf(xf1.w);
        av1[0] = f2bf(xf2.x); av1[1] = f2bf(xf2.y); av1[2] = f2bf(xf2.z); av1[3] = f2bf(xf2.w);
        av1[4] = f2bf(xf3.x); av1[5] = f2bf(xf3.y); av1[6] = f2bf(xf3.z); av1[7] = f2bf(xf3.w);
        *(short8*)&S[(size_t)(ab + aw0) * 8]       = av0;   // k-half 0
        *(short8*)&S[(size_t)(ab + 512 + aw0) * 8] = av1;   // k-half 1

        // only B[kc] is outstanding here; it must land before the MFMA reads it
        asm volatile("s_waitcnt vmcnt(0) lgkmcnt(0)" ::: "memory");
        __builtin_amdgcn_s_barrier();
        __builtin_amdgcn_sched_barrier(0);

        if (kc < 5) {                     // POST-barrier prefetch: x[kc+1] then B[kc+1]
            int k1 = (kc + 1) * 64;       // -> buf (kc+1)&1, whose readers (step kc-1)
            xf0 = *(const float4*)(xrow + k1);             // drained before this barrier
            xf1 = *(const float4*)(xrow + k1 + 4);
            xf2 = *(const float4*)(xrow + k1 + 32);
            xf3 = *(const float4*)(xrow + k1 + 36);
            int nbuf = ((kc + 1) & 1) * 2048;
            #pragma unroll
            for (int r = 0; r < 4; ++r)
                load_lds16(bsrc[r] + k1, S + (size_t)(nbuf + bdstg[r]) * 8);
        }

        #pragma unroll
        for (int kk = 0; kk < 2; ++kk) {
            short8 af0 = *(const short8*)&S[(size_t)(ab + kk * 512 + a_gr) * 8];
            short8 af1 = *(const short8*)&S[(size_t)(ab + kk * 512 + a_gr + 64) * 8];
            #pragma unroll
            for (int e = 0; e < 2; ++e) {
                #pragma unroll
                for (int j = 0; j < 4; ++j) {
                    short8 bf = *(const short8*)&S[(size_t)(bb + kk * 1024 + e * 512 + b_gr + j * 64) * 8];
                    acc[e][0][j] = __builtin_amdgcn_mfma_f32_16x16x32_bf16(af0, bf, acc[e][0][j], 0, 0, 0);
                    acc[e][1][j] = __builtin_amdgcn_mfma_f32_16x16x32_bf16(af1, bf, acc[e][1][j], 0, 0, 0);
                }
            }
        }
    }

    // ---- epilogue: gates+indices to LDS, combine + bias + leaky, scatter store -----
    __syncthreads();                      // full drain before reusing S
    float2* Gp = (float2*)S;                             // 128 * 8B = 1 KB
    int*    Ip = (int*)((char*)S + 1024);                // 128 * 4B
    if (t < 128) {
        int rr = m0 + (t < valid ? t : valid - 1);
        int gid = bidx[p * CAP + rr];
        Ip[t] = gid;
        Gp[t] = tgate[gid];
    }
    float ba_[4], bb_[4];
    #pragma unroll
    for (int j = 0; j < 4; ++j) {
        int oc = n0 + wn * 64 + j * 16 + cc;
        ba_[j] = be[ea * CDIM + oc];
        bb_[j] = be[eb * CDIM + oc];
    }
    __syncthreads();

    #pragma unroll
    for (int i = 0; i < 2; ++i) {
        #pragma unroll
        for (int rr4 = 0; rr4 < 4; ++rr4) {
            int trow = wm * 32 + i * 16 + q * 4 + rr4;   // C/D: col=cc, row=q*4+rr4
            if (trow < valid) {
                float2 g = Gp[trow];
                int gid  = Ip[trow];
                #pragma unroll
                for (int j = 0; j < 4; ++j) {
                    int oc = n0 + wn * 64 + j * 16 + cc;
                    float v = g.x * (acc[0][i][j][rr4] + ba_[j])
                            + g.y * (acc[1][i][j][rr4] + bb_[j]);
                    v = v > 0.0f ? v : 0.01f * v;
                    out[(size_t)gid * CDIM + oc] = v;
                }
            }
        }
    }
}

extern "C" void kernel_launch(void* const* d_in, const int* in_sizes, int n_in,
                              void* d_out, int out_size, void* d_ws, size_t ws_size,
                              hipStream_t stream) {
    const float* x  = (const float*)d_in[0];
    const float* Wg = (const float*)d_in[1];
    const float* We = (const float*)d_in[2];
    const float* be = (const float*)d_in[3];
    float* out = (float*)d_out;

    // ws layout (16B-aligned sections), total ~2.67 MB:
    //   cnt[10]            @ 0       (pad 256)
    //   bidx  10*8192*4    @ 256         = 327680
    //   blkcnt 10*1024*4   @ 327936      = 40960
    //   (gap)              @ 368896      = 40960
    //   tmeta  65536*4     @ 409856      = 262144
    //   tgate  65536*8     @ 672000      = 524288
    //   WeT    5*384*384*2 @ 1196288     = 1474560
    char* ws = (char*)d_ws;
    int*            cnt    = (int*)ws;
    int*            bidx   = (int*)(ws + 256);
    int*            blkcnt = (int*)(ws + 327936);
    int*            tmeta  = (int*)(ws + 409856);
    float2*         tgate  = (float2*)(ws + 672000);
    unsigned short* WeT    = (unsigned short*)(ws + 1196288);

    router_kernel<<<NBLK, 256, 0, stream>>>(x, Wg, blkcnt, tmeta, tgate);
    mid_kernel<<<436, 256, 0, stream>>>(blkcnt, tmeta, bidx, cnt, We, WeT);
    moe_kernel<<<NPAIR * 64 * 3, 512, 0, stream>>>(x, WeT, cnt, bidx, tgate, be, out);
}